// Round 1
// baseline (1260.151 us; speedup 1.0000x reference)
//
#include <hip/hip_runtime.h>
#include <hip/hip_bf16.h>

// Problem constants (Qwen2.5-VL attention block)
#define S_LEN 2048
#define HDIM 3584
#define NH 28
#define NKV 4
#define HD 128
#define NQD 3584   // NH*HD
#define NKVD 512   // NKV*HD

typedef __bf16 bf16x8 __attribute__((ext_vector_type(8)));
typedef float f32x4 __attribute__((ext_vector_type(4)));
typedef unsigned short u16x8 __attribute__((ext_vector_type(8)));

__device__ __forceinline__ unsigned short f2bf(float f) {
  unsigned u = __builtin_bit_cast(unsigned, f);
  u += 0x7fffu + ((u >> 16) & 1u);   // RNE
  return (unsigned short)(u >> 16);
}

__device__ __forceinline__ bf16x8 ld_frag(const unsigned short* p) {
  union { u16x8 u; bf16x8 b; } cv;
  cv.u = *(const u16x8*)p;   // 16B-aligned ds_read_b128
  return cv.b;
}

// ---------------- fp32 -> bf16 bulk convert ----------------
__global__ __launch_bounds__(256) void cvt_kernel(const float* __restrict__ in,
                                                  unsigned short* __restrict__ out,
                                                  int n4) {
  int i = blockIdx.x * 256 + threadIdx.x;
  if (i >= n4) return;
  float4 v = ((const float4*)in)[i];
  ushort4 o;
  o.x = f2bf(v.x); o.y = f2bf(v.y); o.z = f2bf(v.z); o.w = f2bf(v.w);
  ((ushort4*)out)[i] = o;
}

// ---------------- generic bf16 GEMM: C(fp32 MxN) = A(bf16 MxK) @ B(bf16 KxN) + bias ----
// 64x64 tile, BK=32, 4 waves each computing a 32x32 quadrant (2x2 MFMA tiles).
// Verified gfx950 mfma_f32_16x16x32_bf16 layouts:
//   A frag: m=lane&15, k=(lane>>4)*8+j     B frag: n=lane&15, k=(lane>>4)*8+j
//   C/D:    col=lane&15, row=(lane>>4)*4+reg
__global__ __launch_bounds__(256) void gemm_bf16(
    const unsigned short* __restrict__ A, const unsigned short* __restrict__ B,
    const float* __restrict__ bias, float* __restrict__ C, int M, int N, int K) {
  // +8 pad: row stride 80B -> bank step 20 -> only 2-way conflicts (free)
  __shared__ __align__(16) unsigned short As[64][40];   // [m][k]
  __shared__ __align__(16) unsigned short Bs[64][40];   // [n][k] (transposed in staging)
  const int tid = threadIdx.x;
  const int bm = blockIdx.y * 64, bn = blockIdx.x * 64;
  const int wave = tid >> 6, lane = tid & 63;
  const int quad = lane >> 4, l16 = lane & 15;
  const int wrow = (wave >> 1) * 32, wcol = (wave & 1) * 32;
  const int ar = tid >> 2, ac = (tid & 3) * 8;          // A: 64 rows x 4x8 cols
  const int bk = tid >> 3, bn8 = (tid & 7) * 8;         // B: 32 k-rows x 8x8 n
  f32x4 acc[2][2] = {};
  for (int k0 = 0; k0 < K; k0 += 32) {
    u16x8 av = *(const u16x8*)&A[(size_t)(bm + ar) * K + k0 + ac];
    u16x8 bv = *(const u16x8*)&B[(size_t)(k0 + bk) * N + bn + bn8];
    *(u16x8*)&As[ar][ac] = av;
#pragma unroll
    for (int j = 0; j < 8; ++j) Bs[bn8 + j][bk] = bv[j];  // transpose into [n][k]
    __syncthreads();
    bf16x8 a0 = ld_frag(&As[wrow + l16][quad * 8]);
    bf16x8 a1 = ld_frag(&As[wrow + 16 + l16][quad * 8]);
    bf16x8 b0 = ld_frag(&Bs[wcol + l16][quad * 8]);
    bf16x8 b1 = ld_frag(&Bs[wcol + 16 + l16][quad * 8]);
    acc[0][0] = __builtin_amdgcn_mfma_f32_16x16x32_bf16(a0, b0, acc[0][0], 0, 0, 0);
    acc[0][1] = __builtin_amdgcn_mfma_f32_16x16x32_bf16(a0, b1, acc[0][1], 0, 0, 0);
    acc[1][0] = __builtin_amdgcn_mfma_f32_16x16x32_bf16(a1, b0, acc[1][0], 0, 0, 0);
    acc[1][1] = __builtin_amdgcn_mfma_f32_16x16x32_bf16(a1, b1, acc[1][1], 0, 0, 0);
    __syncthreads();
  }
#pragma unroll
  for (int mi = 0; mi < 2; ++mi)
#pragma unroll
    for (int ni = 0; ni < 2; ++ni)
#pragma unroll
      for (int r = 0; r < 4; ++r) {
        int row = bm + wrow + mi * 16 + quad * 4 + r;
        int col = bn + wcol + ni * 16 + l16;
        float v = acc[mi][ni][r];
        if (bias) v += bias[col];
        C[(size_t)row * N + col] = v;
      }
}

// ---------------- mRoPE + head-major transpose + bf16 cast ----------------
// sections [16,24,24]x2 -> sec(d): [0,16)=0 [16,40)=1 [40,64)=2 [64,80)=0 [80,104)=1 [104,128)=2
// rotate_half: d<64 -> -x[d+64]; d>=64 -> x[d-64]
__global__ void rope_kernel(const float* __restrict__ qlin, const float* __restrict__ klin,
                            const float* __restrict__ vlin, const float* __restrict__ cosp,
                            const float* __restrict__ sinp, unsigned short* __restrict__ qr,
                            unsigned short* __restrict__ kr, unsigned short* __restrict__ vh) {
  const int bx = blockIdx.x;
  const int d = threadIdx.x;
  const int sec = d < 16 ? 0 : d < 40 ? 1 : d < 64 ? 2 : d < 80 ? 0 : d < 104 ? 1 : 2;
  if (bx < NH * S_LEN) {
    const int hh = bx / S_LEN, s = bx % S_LEN;
    const float* base = qlin + (size_t)s * NQD + hh * HD;
    float x = base[d];
    float pr = (d < 64) ? -base[d + 64] : base[d - 64];
    float c = cosp[((size_t)sec * S_LEN + s) * HD + d];
    float sn = sinp[((size_t)sec * S_LEN + s) * HD + d];
    qr[((size_t)hh * S_LEN + s) * HD + d] = f2bf(x * c + pr * sn);
  } else if (bx < (NH + NKV) * S_LEN) {
    const int b2 = bx - NH * S_LEN;
    const int hh = b2 / S_LEN, s = b2 % S_LEN;
    const float* base = klin + (size_t)s * NKVD + hh * HD;
    float x = base[d];
    float pr = (d < 64) ? -base[d + 64] : base[d - 64];
    float c = cosp[((size_t)sec * S_LEN + s) * HD + d];
    float sn = sinp[((size_t)sec * S_LEN + s) * HD + d];
    kr[((size_t)hh * S_LEN + s) * HD + d] = f2bf(x * c + pr * sn);
  } else {
    const int b2 = bx - (NH + NKV) * S_LEN;
    const int hh = b2 / S_LEN, s = b2 % S_LEN;
    vh[((size_t)hh * S_LEN + s) * HD + d] = f2bf(vlin[(size_t)s * NKVD + hh * HD + d]);
  }
}

// ---------------- flash attention (no mask, GQA 7:1) ----------------
// block = (q head, 64-row Q tile); 4 waves, each owns a 16-row strip.
__global__ __launch_bounds__(256) void attn_kernel(
    const unsigned short* __restrict__ Q,   // [NH][S][HD] bf16
    const unsigned short* __restrict__ Kh,  // [NKV][S][HD]
    const unsigned short* __restrict__ Vh,  // [NKV][S][HD]
    unsigned short* __restrict__ O) {       // [S][NQD] bf16
  const int h = blockIdx.x;
  const int qt = blockIdx.y;
  const int kvh = h / 7;
  __shared__ __align__(16) unsigned short Qs[64][136];  // [sq][d], +8 pad
  __shared__ __align__(16) unsigned short Ks[64][136];  // [sk][d]
  __shared__ __align__(16) unsigned short Vt[128][72];  // [d][sk] (transposed)
  __shared__ __align__(16) unsigned short Ps[4][16][72];// per-wave P strip [m][sk]
  const int tid = threadIdx.x;
  const int wave = tid >> 6, lane = tid & 63;
  const int quad = lane >> 4, l16 = lane & 15;
  const int lr = tid >> 4;          // loader row 0..15
  const int ld8 = (tid & 15) * 8;   // loader d-offset
#pragma unroll
  for (int p = 0; p < 4; ++p) {
    int row = lr + p * 16;
    *(u16x8*)&Qs[row][ld8] = *(const u16x8*)&Q[((size_t)h * S_LEN + qt * 64 + row) * HD + ld8];
  }
  f32x4 accO[8] = {};
  float mrow[4], lrow[4];
#pragma unroll
  for (int r = 0; r < 4; ++r) { mrow[r] = -3.0e38f; lrow[r] = 0.f; }
  __syncthreads();
  for (int kt = 0; kt < S_LEN / 64; ++kt) {
#pragma unroll
    for (int p = 0; p < 4; ++p) {
      int row = lr + p * 16;
      const size_t gb = ((size_t)kvh * S_LEN + kt * 64 + row) * HD + ld8;
      *(u16x8*)&Ks[row][ld8] = *(const u16x8*)&Kh[gb];
      u16x8 vv = *(const u16x8*)&Vh[gb];
#pragma unroll
      for (int j = 0; j < 8; ++j) Vt[ld8 + j][row] = vv[j];
    }
    __syncthreads();
    // S = Q K^T  (B frag from K row-major: n=sk, k=d contiguous)
    f32x4 accS[4] = {};
#pragma unroll
    for (int ks = 0; ks < 4; ++ks) {
      bf16x8 a = ld_frag(&Qs[wave * 16 + l16][ks * 32 + quad * 8]);
#pragma unroll
      for (int ct = 0; ct < 4; ++ct) {
        bf16x8 b = ld_frag(&Ks[ct * 16 + l16][ks * 32 + quad * 8]);
        accS[ct] = __builtin_amdgcn_mfma_f32_16x16x32_bf16(a, b, accS[ct], 0, 0, 0);
      }
    }
    const float sc = 0.08838834764831845f;  // 1/sqrt(128)
#pragma unroll
    for (int r = 0; r < 4; ++r) {
      float s0 = accS[0][r] * sc, s1 = accS[1][r] * sc;
      float s2 = accS[2][r] * sc, s3 = accS[3][r] * sc;
      float mx = fmaxf(fmaxf(s0, s1), fmaxf(s2, s3));
      mx = fmaxf(mx, __shfl_xor(mx, 1));
      mx = fmaxf(mx, __shfl_xor(mx, 2));
      mx = fmaxf(mx, __shfl_xor(mx, 4));
      mx = fmaxf(mx, __shfl_xor(mx, 8));
      float mn = fmaxf(mrow[r], mx);
      float alpha = __expf(mrow[r] - mn);   // first iter: exp(-big)=0
      mrow[r] = mn;
      float p0 = __expf(s0 - mn), p1 = __expf(s1 - mn);
      float p2 = __expf(s2 - mn), p3 = __expf(s3 - mn);
      float sum = p0 + p1 + p2 + p3;
      sum += __shfl_xor(sum, 1);
      sum += __shfl_xor(sum, 2);
      sum += __shfl_xor(sum, 4);
      sum += __shfl_xor(sum, 8);
      lrow[r] = lrow[r] * alpha + sum;
#pragma unroll
      for (int ct = 0; ct < 8; ++ct) accO[ct][r] *= alpha;
      // C-layout -> A-operand layout via LDS round-trip
      Ps[wave][quad * 4 + r][0 + l16] = f2bf(p0);
      Ps[wave][quad * 4 + r][16 + l16] = f2bf(p1);
      Ps[wave][quad * 4 + r][32 + l16] = f2bf(p2);
      Ps[wave][quad * 4 + r][48 + l16] = f2bf(p3);
    }
    __syncthreads();
    // O += P V  (B frag from Vt: n=d, k=sk contiguous)
#pragma unroll
    for (int ks = 0; ks < 2; ++ks) {
      bf16x8 a = ld_frag(&Ps[wave][l16][ks * 32 + quad * 8]);
#pragma unroll
      for (int ct = 0; ct < 8; ++ct) {
        bf16x8 b = ld_frag(&Vt[ct * 16 + l16][ks * 32 + quad * 8]);
        accO[ct] = __builtin_amdgcn_mfma_f32_16x16x32_bf16(a, b, accO[ct], 0, 0, 0);
      }
    }
    __syncthreads();  // all Ks/Vt/Ps reads done before next staging
  }
#pragma unroll
  for (int ct = 0; ct < 8; ++ct)
#pragma unroll
    for (int r = 0; r < 4; ++r) {
      int srow = qt * 64 + wave * 16 + quad * 4 + r;
      int d = ct * 16 + l16;
      O[(size_t)srow * NQD + h * HD + d] = f2bf(accO[ct][r] / lrow[r]);
    }
}

extern "C" void kernel_launch(void* const* d_in, const int* in_sizes, int n_in,
                              void* d_out, int out_size, void* d_ws, size_t ws_size,
                              hipStream_t stream) {
  const float* hidden = (const float*)d_in[0];
  const float* cosp = (const float*)d_in[1];
  const float* sinp = (const float*)d_in[2];
  const float* Wq = (const float*)d_in[3];
  const float* bq = (const float*)d_in[4];
  const float* Wk = (const float*)d_in[5];
  const float* bk = (const float*)d_in[6];
  const float* Wv = (const float*)d_in[7];
  const float* bv = (const float*)d_in[8];
  const float* Wo = (const float*)d_in[9];
  float* out = (float*)d_out;

  const size_t HID_N = (size_t)S_LEN * HDIM;   // 7,340,032
  const size_t WQ_N = (size_t)HDIM * NQD;      // 12,845,056
  const size_t WK_N = (size_t)HDIM * NKVD;     // 1,835,008
  const size_t KV_N = (size_t)S_LEN * NKVD;    // 1,048,576

  char* p = (char*)d_ws;
  size_t off = 0;
  auto take = [&](size_t b) { void* r = p + off; off += (b + 255) & ~(size_t)255; return r; };
  unsigned short* hid_bf = (unsigned short*)take(HID_N * 2);
  unsigned short* wq_bf = (unsigned short*)take(WQ_N * 2);
  unsigned short* wk_bf = (unsigned short*)take(WK_N * 2);
  unsigned short* wv_bf = (unsigned short*)take(WK_N * 2);
  unsigned short* wo_bf = (unsigned short*)take(WQ_N * 2);
  float* q_lin = (float*)take(HID_N * 4);
  float* k_lin = (float*)take(KV_N * 4);
  float* v_lin = (float*)take(KV_N * 4);
  unsigned short* q_rot = (unsigned short*)take(HID_N * 2);
  unsigned short* k_rot = (unsigned short*)take(KV_N * 2);
  unsigned short* v_hm = (unsigned short*)take(KV_N * 2);
  // attn output aliases q_lin (dead after rope); bf16 [S][NQD]
  unsigned short* attn_bf = (unsigned short*)q_lin;
  if (off > ws_size) return;  // workspace too small: leave output poisoned (loud failure)

  cvt_kernel<<<(int)((HID_N / 4 + 255) / 256), 256, 0, stream>>>(hidden, hid_bf, (int)(HID_N / 4));
  cvt_kernel<<<(int)((WQ_N / 4 + 255) / 256), 256, 0, stream>>>(Wq, wq_bf, (int)(WQ_N / 4));
  cvt_kernel<<<(int)((WK_N / 4 + 255) / 256), 256, 0, stream>>>(Wk, wk_bf, (int)(WK_N / 4));
  cvt_kernel<<<(int)((WK_N / 4 + 255) / 256), 256, 0, stream>>>(Wv, wv_bf, (int)(WK_N / 4));
  cvt_kernel<<<(int)((WQ_N / 4 + 255) / 256), 256, 0, stream>>>(Wo, wo_bf, (int)(WQ_N / 4));

  gemm_bf16<<<dim3(NQD / 64, S_LEN / 64), 256, 0, stream>>>(hid_bf, wq_bf, bq, q_lin, S_LEN, NQD, HDIM);
  gemm_bf16<<<dim3(NKVD / 64, S_LEN / 64), 256, 0, stream>>>(hid_bf, wk_bf, bk, k_lin, S_LEN, NKVD, HDIM);
  gemm_bf16<<<dim3(NKVD / 64, S_LEN / 64), 256, 0, stream>>>(hid_bf, wv_bf, bv, v_lin, S_LEN, NKVD, HDIM);

  rope_kernel<<<(NH + 2 * NKV) * S_LEN, HD, 0, stream>>>(q_lin, k_lin, v_lin, cosp, sinp,
                                                         q_rot, k_rot, v_hm);

  attn_kernel<<<dim3(NH, S_LEN / 64), 256, 0, stream>>>(q_rot, k_rot, v_hm, attn_bf);

  gemm_bf16<<<dim3(NQD / 64, S_LEN / 64), 256, 0, stream>>>(attn_bf, wo_bf, nullptr, out,
                                                            S_LEN, NQD, NQD);
}

// Round 3
// 565.359 us; speedup vs baseline: 2.2289x; 2.2289x over previous
//
#include <hip/hip_runtime.h>
#include <hip/hip_bf16.h>

#define S_LEN 2048
#define HDIM 3584
#define NH 28
#define NKV 4
#define HD 128
#define NQD 3584   // NH*HD
#define NKVD 512   // NKV*HD
#define NQKV 4608  // NQD + 2*NKVD

typedef __bf16 bf16x8 __attribute__((ext_vector_type(8)));
typedef float f32x4 __attribute__((ext_vector_type(4)));
typedef unsigned short u16x8 __attribute__((ext_vector_type(8)));

__device__ __forceinline__ unsigned short f2bf(float f) {
  unsigned u = __builtin_bit_cast(unsigned, f);
  u += 0x7fffu + ((u >> 16) & 1u);   // RNE
  return (unsigned short)(u >> 16);
}

__device__ __forceinline__ bf16x8 ld_frag(const unsigned short* p) {
  union { u16x8 u; bf16x8 b; } cv;
  cv.u = *(const u16x8*)p;   // 16B ds_read_b128 / global_load_dwordx4
  return cv.b;
}

// async global->LDS, 16B per lane; lds dest is wave-uniform base + lane*16
__device__ __forceinline__ void async_cp16(const void* g, void* lds) {
  __builtin_amdgcn_global_load_lds(
      (const __attribute__((address_space(1))) unsigned int*)g,
      (__attribute__((address_space(3))) unsigned int*)lds, 16, 0, 0);
}

// ---------------- fp32 -> bf16 flat convert ----------------
__global__ __launch_bounds__(256) void cvt_kernel(const float* __restrict__ in,
                                                  unsigned short* __restrict__ out, int n4) {
  int i = blockIdx.x * 256 + threadIdx.x;
  if (i >= n4) return;
  float4 v = ((const float4*)in)[i];
  ushort4 o;
  o.x = f2bf(v.x); o.y = f2bf(v.y); o.z = f2bf(v.z); o.w = f2bf(v.w);
  ((ushort4*)out)[i] = o;
}

// ---------------- tiled transpose + fp32->bf16: out[c][r] = in[r][c] ----------------
__global__ __launch_bounds__(256) void tcvt(const float* __restrict__ in,
                                            unsigned short* __restrict__ out,
                                            int R, int C, int ldin) {
  __shared__ float t[32][33];
  const int tx = threadIdx.x, ty = threadIdx.y;   // 32 x 8
  const int r0 = blockIdx.y * 32, c0 = blockIdx.x * 32;
#pragma unroll
  for (int j = 0; j < 4; ++j)
    t[ty + 8 * j][tx] = in[(size_t)(r0 + ty + 8 * j) * ldin + c0 + tx];
  __syncthreads();
#pragma unroll
  for (int j = 0; j < 4; ++j)
    out[(size_t)(c0 + ty + 8 * j) * R + r0 + tx] = f2bf(t[tx][ty + 8 * j]);
}

// ---------------- concat bias [bq | bk | bv] ----------------
__global__ void biascat(const float* __restrict__ bq, const float* __restrict__ bk,
                        const float* __restrict__ bv, float* __restrict__ o) {
  int i = blockIdx.x * 256 + threadIdx.x;
  if (i < NQD) o[i] = bq[i];
  else if (i < NQD + NKVD) o[i] = bk[i - NQD];
  else if (i < NQKV) o[i] = bv[i - NQD - NKVD];
}

// ---------------- m97-style 128x128 bf16 GEMM, global_load_lds staging ----------------
// C(fp32 MxN) = A(bf16 [M][K]) @ Bt(bf16 [N][K])^T + bias
// LDS: unpadded [row][32k] with XOR chunk swizzle kq' = kq ^ ((row>>1)&3) -> 2-way max
__global__ __launch_bounds__(256) void gemm128(
    const unsigned short* __restrict__ A, const unsigned short* __restrict__ Bt,
    const float* __restrict__ bias, float* __restrict__ C, int M, int N, int K) {
  __shared__ __align__(16) unsigned short As[128 * 32];
  __shared__ __align__(16) unsigned short Bs[128 * 32];
  const int tid = threadIdx.x, wave = tid >> 6, lane = tid & 63;
  const int quad = lane >> 4, l16 = lane & 15;
  const int bm = blockIdx.y * 128, bn = blockIdx.x * 128;
  const int wrow = (wave >> 1) * 64, wcol = (wave & 1) * 64;
  int srow[2], scol[2], sg[2];
#pragma unroll
  for (int t = 0; t < 2; ++t) {
    int g = (wave * 2 + t) * 64 + lane;       // chunk id 0..511
    sg[t] = g;
    srow[t] = g >> 2;                          // 0..127
    scol[t] = ((g & 3) ^ ((srow[t] >> 1) & 3)) * 8;  // element offset of 16B chunk
  }
  f32x4 acc[4][4] = {};
  for (int k0 = 0; k0 < K; k0 += 32) {
#pragma unroll
    for (int t = 0; t < 2; ++t) {
      async_cp16(&A[(size_t)(bm + srow[t]) * K + k0 + scol[t]], &As[(size_t)sg[t] * 8]);
      async_cp16(&Bt[(size_t)(bn + srow[t]) * K + k0 + scol[t]], &Bs[(size_t)sg[t] * 8]);
    }
    __syncthreads();
    bf16x8 af[4], bfr[4];
#pragma unroll
    for (int t = 0; t < 4; ++t) {
      int ra = wrow + t * 16 + l16;
      af[t] = ld_frag(&As[ra * 32 + ((quad ^ ((ra >> 1) & 3)) << 3)]);
      int rb = wcol + t * 16 + l16;
      bfr[t] = ld_frag(&Bs[rb * 32 + ((quad ^ ((rb >> 1) & 3)) << 3)]);
    }
#pragma unroll
    for (int i = 0; i < 4; ++i)
#pragma unroll
      for (int j = 0; j < 4; ++j)
        acc[i][j] = __builtin_amdgcn_mfma_f32_16x16x32_bf16(af[i], bfr[j], acc[i][j], 0, 0, 0);
    __syncthreads();
  }
#pragma unroll
  for (int i = 0; i < 4; ++i) {
    int row = bm + wrow + i * 16 + quad * 4;
#pragma unroll
    for (int j = 0; j < 4; ++j) {
      int col = bn + wcol + j * 16 + l16;
      float bv = bias ? bias[col] : 0.f;
#pragma unroll
      for (int r = 0; r < 4; ++r)
        C[(size_t)(row + r) * N + col] = acc[i][j][r] + bv;
    }
  }
}

// ---------------- mRoPE (q scaled by 1/sqrt(HD)*log2(e)) ----------------
// sections: [0,16)=0 [16,40)=1 [40,64)=2 [64,80)=0 [80,104)=1 [104,128)=2
#define QSCALE (0.08838834764831845f * 1.4426950408889634f)
__global__ void rope2(const float* __restrict__ qkv,   // [S][4608] fp32
                      const float* __restrict__ cosp, const float* __restrict__ sinp,
                      unsigned short* __restrict__ qr,  // [NH][S][HD] bf16 (scaled)
                      unsigned short* __restrict__ kr) { // [NKV][S][HD] bf16
  const int s = blockIdx.x;
  const int hy = blockIdx.y;   // 0..27 -> q head, 28..31 -> k head
  const int d = threadIdx.x;
  const int sec = d < 16 ? 0 : d < 40 ? 1 : d < 64 ? 2 : d < 80 ? 0 : d < 104 ? 1 : 2;
  const bool isq = hy < NH;
  const int off = isq ? hy * HD : NQD + (hy - NH) * HD;
  const float* base = qkv + (size_t)s * NQKV + off;
  float x = base[d];
  float pr = (d < 64) ? -base[d + 64] : base[d - 64];
  float c = cosp[((size_t)sec * S_LEN + s) * HD + d];
  float sn = sinp[((size_t)sec * S_LEN + s) * HD + d];
  float v = x * c + pr * sn;
  if (isq) qr[((size_t)hy * S_LEN + s) * HD + d] = f2bf(v * QSCALE);
  else kr[((size_t)(hy - NH) * S_LEN + s) * HD + d] = f2bf(v);
}

// ---------------- flash attention, S^T formulation ----------------
// block = (head, 64 q rows); 4 waves x 16-q strips. Q in registers (B-operand).
// S^T = K.Q^T : A=K[sk][d], B=Q[q][d] -> C: col=l16=q, row=quad*4+r=sk_local.
// P^T -> PV B-operand via channel register shuffles (value pushed is uniform per
// shuffle op: each source lane pushes pk[c]; dest selects channel 2ks+(quad>>1)).
// O^T = Vt.P : A=Vt[d][sk], B=P[q][sk] -> C: col=q, row=d_local.
__global__ __launch_bounds__(256) void attn2(
    const unsigned short* __restrict__ Q,   // [NH][S][HD] bf16, pre-scaled
    const unsigned short* __restrict__ Kh,  // [NKV][S][HD] bf16
    const unsigned short* __restrict__ Vt,  // [NKVD][S] bf16 (d-major)
    unsigned short* __restrict__ O) {       // [S][NQD] bf16
  __shared__ __align__(16) unsigned short Ks[64 * 128];  // [sk][d], swizzled chunks
  __shared__ __align__(16) unsigned short Vs[128 * 64];  // [d][sk], swizzled chunks
  const int tid = threadIdx.x, wave = tid >> 6, lane = tid & 63;
  const int quad = lane >> 4, l16 = lane & 15;
  // XCD swizzle: blocks b%8 spread over XCDs; each XCD serves one kv head
  const int b = blockIdx.x;
  const int xcd = b & 7, slot = b >> 3;          // slot 0..111
  const int kvh = xcd & 3;
  const int strip = (xcd >> 2) * 112 + slot;     // 0..223
  const int h = kvh * 7 + (strip >> 5);
  const int qt = strip & 31;
  // Q preload as B-operand frags: n=l16 -> q row, k=quad*8+j -> d
  bf16x8 qf[4];
  const size_t qrow = ((size_t)h * S_LEN + qt * 64 + wave * 16 + l16) * HD;
#pragma unroll
  for (int kc = 0; kc < 4; ++kc)
    qf[kc] = ld_frag(&Q[qrow + kc * 32 + quad * 8]);
  f32x4 accO[8] = {};
  float m = -3.0e38f, lsum = 0.f;
  for (int kt = 0; kt < S_LEN / 64; ++kt) {
    // stage K tile (64x128, 1024 chunks) and V tile (128x64, 1024 chunks)
#pragma unroll
    for (int t = 0; t < 4; ++t) {
      int g = (wave * 4 + t) * 64 + lane;
      int krow = g >> 4, kq = ((g & 15) ^ (krow & 15)) * 8;
      async_cp16(&Kh[((size_t)kvh * S_LEN + kt * 64 + krow) * HD + kq], &Ks[(size_t)g * 8]);
      int vrow = g >> 3, vc = ((g & 7) ^ (vrow & 7)) * 8;
      async_cp16(&Vt[((size_t)(kvh * HD) + vrow) * S_LEN + kt * 64 + vc], &Vs[(size_t)g * 8]);
    }
    __syncthreads();
    // S^T: 4 sk-tiles x 4 k-chunks
    f32x4 st[4] = {};
#pragma unroll
    for (int s4 = 0; s4 < 4; ++s4) {
      int row = s4 * 16 + l16;
#pragma unroll
      for (int kc = 0; kc < 4; ++kc) {
        bf16x8 a = ld_frag(&Ks[row * 128 + (((kc * 4 + quad) ^ (row & 15)) << 3)]);
        st[s4] = __builtin_amdgcn_mfma_f32_16x16x32_bf16(a, qf[kc], st[s4], 0, 0, 0);
      }
    }
    // online softmax in log2 domain (scale folded into Q)
    float mt = st[0][0];
#pragma unroll
    for (int s4 = 0; s4 < 4; ++s4)
#pragma unroll
      for (int r = 0; r < 4; ++r) mt = fmaxf(mt, st[s4][r]);
    mt = fmaxf(mt, __shfl_xor(mt, 16));
    mt = fmaxf(mt, __shfl_xor(mt, 32));
    float mn = fmaxf(m, mt);
    float alpha = exp2f(m - mn);
    m = mn;
    float sum = 0.f;
#pragma unroll
    for (int s4 = 0; s4 < 4; ++s4)
#pragma unroll
      for (int r = 0; r < 4; ++r) {
        float p = exp2f(st[s4][r] - mn);
        st[s4][r] = p;
        sum += p;
      }
    sum += __shfl_xor(sum, 16);
    sum += __shfl_xor(sum, 32);
    lsum = lsum * alpha + sum;
#pragma unroll
    for (int dt = 0; dt < 8; ++dt) accO[dt] *= alpha;
    // pack p (bf16 pairs r0r1, r2r3): pk[s4][0]=(r0,r1), pk[s4][1]=(r2,r3)
    unsigned pk[4][2];
#pragma unroll
    for (int s4 = 0; s4 < 4; ++s4) {
      pk[s4][0] = (unsigned)f2bf(st[s4][0]) | ((unsigned)f2bf(st[s4][1]) << 16);
      pk[s4][1] = (unsigned)f2bf(st[s4][2]) | ((unsigned)f2bf(st[s4][3]) << 16);
    }
    // channel shuffles: shuffled VALUE has uniform tile index c (so every source
    // lane pushes the same tile); dest lane (quad) needs source quads
    // 2*(quad&1) and 2*(quad&1)+1, tile c = 2ks + (quad>>1).
    const int src0 = ((quad & 1) * 2) * 16 + l16;
    const int src1 = src0 + 16;
    unsigned sh[4][4];
#pragma unroll
    for (int c = 0; c < 4; ++c) {
      sh[c][0] = (unsigned)__shfl((int)pk[c][0], src0);
      sh[c][1] = (unsigned)__shfl((int)pk[c][1], src0);
      sh[c][2] = (unsigned)__shfl((int)pk[c][0], src1);
      sh[c][3] = (unsigned)__shfl((int)pk[c][1], src1);
    }
    const bool hi = (quad >> 1) != 0;
    bf16x8 pb[2];
#pragma unroll
    for (int ks = 0; ks < 2; ++ks) {
      union { unsigned u[4]; bf16x8 bv; } cv;
#pragma unroll
      for (int w = 0; w < 4; ++w)
        cv.u[w] = hi ? sh[2 * ks + 1][w] : sh[2 * ks][w];
      pb[ks] = cv.bv;
    }
    // O^T += Vt . P : 8 d-tiles x 2 sk-chunks
#pragma unroll
    for (int dt = 0; dt < 8; ++dt) {
      int row = dt * 16 + l16;
#pragma unroll
      for (int ks = 0; ks < 2; ++ks) {
        bf16x8 a = ld_frag(&Vs[row * 64 + (((ks * 4 + quad) ^ (row & 7)) << 3)]);
        accO[dt] = __builtin_amdgcn_mfma_f32_16x16x32_bf16(a, pb[ks], accO[dt], 0, 0, 0);
      }
    }
    __syncthreads();
  }
  // epilogue: accO col=l16=q, row=quad*4+r=d_local; packed dword stores
  float rl = 1.f / lsum;
  const size_t orow = ((size_t)(qt * 64 + wave * 16 + l16)) * NQD + h * HD;
#pragma unroll
  for (int dt = 0; dt < 8; ++dt) {
    unsigned w0 = (unsigned)f2bf(accO[dt][0] * rl) | ((unsigned)f2bf(accO[dt][1] * rl) << 16);
    unsigned w1 = (unsigned)f2bf(accO[dt][2] * rl) | ((unsigned)f2bf(accO[dt][3] * rl) << 16);
    *(unsigned*)&O[orow + dt * 16 + quad * 4] = w0;
    *(unsigned*)&O[orow + dt * 16 + quad * 4 + 2] = w1;
  }
}

extern "C" void kernel_launch(void* const* d_in, const int* in_sizes, int n_in,
                              void* d_out, int out_size, void* d_ws, size_t ws_size,
                              hipStream_t stream) {
  const float* hidden = (const float*)d_in[0];
  const float* cosp = (const float*)d_in[1];
  const float* sinp = (const float*)d_in[2];
  const float* Wq = (const float*)d_in[3];
  const float* bq = (const float*)d_in[4];
  const float* Wk = (const float*)d_in[5];
  const float* bk = (const float*)d_in[6];
  const float* Wv = (const float*)d_in[7];
  const float* bv = (const float*)d_in[8];
  const float* Wo = (const float*)d_in[9];
  float* out = (float*)d_out;

  const size_t HID_N = (size_t)S_LEN * HDIM;
  const size_t WQ_N = (size_t)HDIM * NQD;
  const size_t KV_N = (size_t)S_LEN * NKVD;

  char* p = (char*)d_ws;
  size_t off = 0;
  auto take = [&](size_t bytes) {
    void* r = p + off; off += (bytes + 255) & ~(size_t)255; return r;
  };
  unsigned short* hid_bf = (unsigned short*)take(HID_N * 2);
  unsigned short* wqkvT = (unsigned short*)take((size_t)NQKV * HDIM * 2);
  unsigned short* woT = (unsigned short*)take(WQ_N * 2);
  float* bcat = (float*)take(NQKV * 4);
  float* qkv_lin = (float*)take((size_t)S_LEN * NQKV * 4);
  unsigned short* q_rot = (unsigned short*)take(HID_N * 2);
  unsigned short* k_rot = (unsigned short*)take(KV_N * 2);
  unsigned short* v_t = (unsigned short*)take(KV_N * 2);
  // attn output aliases qkv_lin (dead after rope + v transpose)
  unsigned short* attn_bf = (unsigned short*)qkv_lin;
  if (off > ws_size) return;   // loud failure: output stays poisoned

  // bf16 conversions / weight transposes
  cvt_kernel<<<(int)((HID_N / 4 + 255) / 256), 256, 0, stream>>>(hidden, hid_bf, (int)(HID_N / 4));
  dim3 tb(32, 8);
  tcvt<<<dim3(NQD / 32, HDIM / 32), tb, 0, stream>>>(Wq, wqkvT, HDIM, NQD, NQD);
  tcvt<<<dim3(NKVD / 32, HDIM / 32), tb, 0, stream>>>(Wk, wqkvT + (size_t)NQD * HDIM, HDIM, NKVD, NKVD);
  tcvt<<<dim3(NKVD / 32, HDIM / 32), tb, 0, stream>>>(Wv, wqkvT + (size_t)(NQD + NKVD) * HDIM, HDIM, NKVD, NKVD);
  tcvt<<<dim3(NQD / 32, NQD / 32), tb, 0, stream>>>(Wo, woT, NQD, NQD, NQD);
  biascat<<<(NQKV + 255) / 256, 256, 0, stream>>>(bq, bk, bv, bcat);

  // fused QKV projection: [2048][3584] @ [3584][4608] -> [2048][4608] fp32
  gemm128<<<dim3(NQKV / 128, S_LEN / 128), 256, 0, stream>>>(hid_bf, wqkvT, bcat, qkv_lin,
                                                             S_LEN, NQKV, HDIM);
  // mRoPE for q,k -> head-major bf16
  rope2<<<dim3(S_LEN, NH + NKV), HD, 0, stream>>>(qkv_lin, cosp, sinp, q_rot, k_rot);
  // V: transpose-cast [2048][512] (stride 4608) -> [512][2048] bf16
  tcvt<<<dim3(NKVD / 32, S_LEN / 32), tb, 0, stream>>>(qkv_lin + (NQD + NKVD), v_t,
                                                       S_LEN, NKVD, NQKV);
  // attention
  attn2<<<NH * (S_LEN / 64), 256, 0, stream>>>(q_rot, k_rot, v_t, attn_bf);
  // output projection: [2048][3584] @ [3584][3584] -> fp32 out
  gemm128<<<dim3(NQD / 128, S_LEN / 128), 256, 0, stream>>>(attn_bf, woT, nullptr, out,
                                                            S_LEN, NQD, NQD);
}

// Round 4
// 545.643 us; speedup vs baseline: 2.3095x; 1.0361x over previous
//
#include <hip/hip_runtime.h>
#include <hip/hip_bf16.h>

#define S_LEN 2048
#define HDIM 3584
#define NH 28
#define NKV 4
#define HD 128
#define NQD 3584   // NH*HD
#define NKVD 512   // NKV*HD
#define NQKV 4608  // NQD + 2*NKVD

typedef __bf16 bf16x8 __attribute__((ext_vector_type(8)));
typedef float f32x4 __attribute__((ext_vector_type(4)));
typedef unsigned short u16x8 __attribute__((ext_vector_type(8)));

__device__ __forceinline__ unsigned short f2bf(float f) {
  unsigned u = __builtin_bit_cast(unsigned, f);
  u += 0x7fffu + ((u >> 16) & 1u);   // RNE
  return (unsigned short)(u >> 16);
}

__device__ __forceinline__ bf16x8 ld_frag(const unsigned short* p) {
  union { u16x8 u; bf16x8 b; } cv;
  cv.u = *(const u16x8*)p;   // 16B ds_read_b128
  return cv.b;
}

// async global->LDS, 16B per lane; lds dest is wave-uniform base + lane*16
__device__ __forceinline__ void async_cp16(const void* g, void* lds) {
  __builtin_amdgcn_global_load_lds(
      (const __attribute__((address_space(1))) unsigned int*)g,
      (__attribute__((address_space(3))) unsigned int*)lds, 16, 0, 0);
}

// ---------------- fp32 -> bf16 flat convert ----------------
__global__ __launch_bounds__(256) void cvt_kernel(const float* __restrict__ in,
                                                  unsigned short* __restrict__ out, int n4) {
  int i = blockIdx.x * 256 + threadIdx.x;
  if (i >= n4) return;
  float4 v = ((const float4*)in)[i];
  ushort4 o;
  o.x = f2bf(v.x); o.y = f2bf(v.y); o.z = f2bf(v.z); o.w = f2bf(v.w);
  ((ushort4*)out)[i] = o;
}

// ---------------- tiled transpose + fp32->bf16: out[c][r] = in[r][c] ----------------
__global__ __launch_bounds__(256) void tcvt(const float* __restrict__ in,
                                            unsigned short* __restrict__ out,
                                            int R, int C, int ldin) {
  __shared__ float t[32][33];
  const int tx = threadIdx.x, ty = threadIdx.y;   // 32 x 8
  const int r0 = blockIdx.y * 32, c0 = blockIdx.x * 32;
#pragma unroll
  for (int j = 0; j < 4; ++j)
    t[ty + 8 * j][tx] = in[(size_t)(r0 + ty + 8 * j) * ldin + c0 + tx];
  __syncthreads();
#pragma unroll
  for (int j = 0; j < 4; ++j)
    out[(size_t)(c0 + ty + 8 * j) * R + r0 + tx] = f2bf(t[tx][ty + 8 * j]);
}

// ---------------- concat bias [bq | bk | bv] ----------------
__global__ void biascat(const float* __restrict__ bq, const float* __restrict__ bk,
                        const float* __restrict__ bv, float* __restrict__ o) {
  int i = blockIdx.x * 256 + threadIdx.x;
  if (i < NQD) o[i] = bq[i];
  else if (i < NQD + NKVD) o[i] = bk[i - NQD];
  else if (i < NQKV) o[i] = bv[i - NQD - NKVD];
}

// ---------------- build mrope'd cos/sin, transposed: cmT[d][s] ----------------
// sections: [0,16)=0 [16,40)=1 [40,64)=2 [64,80)=0 [80,104)=1 [104,128)=2
__global__ void mrope_build(const float* __restrict__ cosp, const float* __restrict__ sinp,
                            float* __restrict__ cmT, float* __restrict__ smT) {
  const int d = blockIdx.y;
  const int s = blockIdx.x * 256 + threadIdx.x;
  const int sec = d < 16 ? 0 : d < 40 ? 1 : d < 64 ? 2 : d < 80 ? 0 : d < 104 ? 1 : 2;
  const size_t src = ((size_t)sec * S_LEN + s) * HD + d;
  cmT[(size_t)d * S_LEN + s] = cosp[src];
  smT[(size_t)d * S_LEN + s] = sinp[src];
}

// ---------------- 128x128 bf16 GEMM, BK=64, global_load_lds staging ----------------
// Wave owns rows [wrow, wrow+64) and cols {wc2+0..31} U {wc2+64..95} (closed under ^64
// so the rope partner d^64 is register j^2 in the same lane).
// LDS chunk swizzle: position (row,p) holds logical k-chunk p^(row&7) -> 2-way max.
// MODE 0: fp32 C out (+bias). MODE 1: fused QKV epilogue (rope q/k, transpose-cast v).
#define QSCALE (0.08838834764831845f * 1.4426950408889634f)
template <int MODE>
__global__ __launch_bounds__(256) void gemm_k64(
    const unsigned short* __restrict__ A,   // [M][K] bf16
    const unsigned short* __restrict__ Bt,  // [N][K] bf16
    const float* __restrict__ bias,         // [N] or null
    const float* __restrict__ cmT,          // [HD][S] (MODE 1)
    const float* __restrict__ smT,
    float* __restrict__ Cout,               // MODE 0
    unsigned short* __restrict__ qr,        // MODE 1: [NH][S][HD]
    unsigned short* __restrict__ kr,        // MODE 1: [NKV][S][HD]
    unsigned short* __restrict__ vt,        // MODE 1: [NKVD][S]
    int M, int N, int K) {
  __shared__ __align__(16) unsigned short As[128 * 64];
  __shared__ __align__(16) unsigned short Bs[128 * 64];
  const int tid = threadIdx.x, wave = tid >> 6;
  const int lane = tid & 63, quad = lane >> 4, l16 = lane & 15;
  const int bm = blockIdx.y * 128, bn = blockIdx.x * 128;
  const int wrow = (wave >> 1) * 64, wc2 = (wave & 1) * 32;
  f32x4 acc[4][4] = {};
  for (int k0 = 0; k0 < K; k0 += 64) {
#pragma unroll
    for (int t = 0; t < 4; ++t) {
      int g = t * 256 + tid;                 // chunk 0..1023
      int row = g >> 3;
      int c = (g & 7) ^ (row & 7);           // logical k-chunk to fetch
      async_cp16(&A[(size_t)(bm + row) * K + k0 + c * 8], &As[(size_t)g * 8]);
      async_cp16(&Bt[(size_t)(bn + row) * K + k0 + c * 8], &Bs[(size_t)g * 8]);
    }
    __syncthreads();
    bf16x8 af[4][2], bfr[4][2];
#pragma unroll
    for (int i = 0; i < 4; ++i) {
      int ra = wrow + i * 16 + l16;
#pragma unroll
      for (int ks = 0; ks < 2; ++ks)
        af[i][ks] = ld_frag(&As[ra * 64 + (((ks * 4 + quad) ^ (ra & 7)) << 3)]);
    }
#pragma unroll
    for (int j = 0; j < 4; ++j) {
      int rb = wc2 + (j & 1) * 16 + (j >> 1) * 64 + l16;
#pragma unroll
      for (int ks = 0; ks < 2; ++ks)
        bfr[j][ks] = ld_frag(&Bs[rb * 64 + (((ks * 4 + quad) ^ (rb & 7)) << 3)]);
    }
#pragma unroll
    for (int ks = 0; ks < 2; ++ks)
#pragma unroll
      for (int i = 0; i < 4; ++i)
#pragma unroll
        for (int j = 0; j < 4; ++j)
          acc[i][j] = __builtin_amdgcn_mfma_f32_16x16x32_bf16(af[i][ks], bfr[j][ks],
                                                              acc[i][j], 0, 0, 0);
    __syncthreads();
  }
  int dcol[4];
  float bj[4];
#pragma unroll
  for (int j = 0; j < 4; ++j) {
    dcol[j] = wc2 + (j & 1) * 16 + (j >> 1) * 64 + l16;
    bj[j] = bias ? bias[bn + dcol[j]] : 0.f;
  }
  if (MODE == 0) {
#pragma unroll
    for (int i = 0; i < 4; ++i) {
      int row0 = bm + wrow + i * 16 + quad * 4;
#pragma unroll
      for (int j = 0; j < 4; ++j)
#pragma unroll
        for (int r = 0; r < 4; ++r)
          Cout[(size_t)(row0 + r) * N + bn + dcol[j]] = acc[i][j][r] + bj[j];
    }
  } else {
    const int tile = blockIdx.x;  // 0..27 q head | 28..31 k head | 32..35 v head
    if (tile < 32) {
      const bool isq = tile < 28;
      unsigned short* dst = isq ? (qr + (size_t)tile * S_LEN * HD)
                                : (kr + (size_t)(tile - 28) * S_LEN * HD);
      const float scl = isq ? QSCALE : 1.0f;
#pragma unroll
      for (int i = 0; i < 4; ++i) {
        int srow = bm + wrow + i * 16 + quad * 4;
#pragma unroll
        for (int j = 0; j < 4; ++j) {
          int d = dcol[j];
          f32x4 cm4 = *(const f32x4*)&cmT[(size_t)d * S_LEN + srow];
          f32x4 sm4 = *(const f32x4*)&smT[(size_t)d * S_LEN + srow];
#pragma unroll
          for (int r = 0; r < 4; ++r) {
            float x = acc[i][j][r] + bj[j];
            float px = acc[i][j ^ 2][r] + bj[j ^ 2];
            float pr = (j < 2) ? -px : px;   // rotate_half partner (d^64, same lane)
            dst[(size_t)(srow + r) * HD + d] = f2bf((x * cm4[r] + pr * sm4[r]) * scl);
          }
        }
      }
    } else {
      const int kvh = tile - 32;
#pragma unroll
      for (int i = 0; i < 4; ++i) {
        int srow = bm + wrow + i * 16 + quad * 4;
#pragma unroll
        for (int j = 0; j < 4; ++j) {
          int d = dcol[j];
          unsigned w0 = (unsigned)f2bf(acc[i][j][0] + bj[j]) |
                        ((unsigned)f2bf(acc[i][j][1] + bj[j]) << 16);
          unsigned w1 = (unsigned)f2bf(acc[i][j][2] + bj[j]) |
                        ((unsigned)f2bf(acc[i][j][3] + bj[j]) << 16);
          unsigned short* vp = &vt[(size_t)(kvh * HD + d) * S_LEN + srow];
          *(unsigned*)vp = w0;
          *(unsigned*)(vp + 2) = w1;
        }
      }
    }
  }
}

// ---------------- flash attention, S^T formulation, tile-0 max ----------------
// block = (head, 64 q rows); 4 waves x 16-q strips. Q in registers (B-operand).
// S^T = K.Q^T : C col=l16=q, row=quad*4+r=sk_local. Tile-0 row max (scores bounded;
// overflow would be inf -> loud fail). P truncated to bf16 (RTZ); lsum sums the
// SAME truncated values so num/denom errors cancel. No accO rescale.
__global__ __launch_bounds__(256) void attn2(
    const unsigned short* __restrict__ Q,   // [NH][S][HD] bf16, pre-scaled by QSCALE
    const unsigned short* __restrict__ Kh,  // [NKV][S][HD] bf16
    const unsigned short* __restrict__ Vt,  // [NKVD][S] bf16 (d-major)
    unsigned short* __restrict__ O) {       // [S][NQD] bf16
  __shared__ __align__(16) unsigned short Ks[64 * 128];
  __shared__ __align__(16) unsigned short Vs[128 * 64];
  const int tid = threadIdx.x, wave = tid >> 6, lane = tid & 63;
  const int quad = lane >> 4, l16 = lane & 15;
  const int b = blockIdx.x;
  const int xcd = b & 7, slot = b >> 3;
  const int kvh = xcd & 3;
  const int strip = (xcd >> 2) * 112 + slot;
  const int h = kvh * 7 + (strip >> 5);
  const int qt = strip & 31;
  bf16x8 qf[4];
  const size_t qrow = ((size_t)h * S_LEN + qt * 64 + wave * 16 + l16) * HD;
#pragma unroll
  for (int kc = 0; kc < 4; ++kc)
    qf[kc] = ld_frag(&Q[qrow + kc * 32 + quad * 8]);
  f32x4 accO[8] = {};
  float m = 0.f, lsum = 0.f;
  for (int kt = 0; kt < S_LEN / 64; ++kt) {
#pragma unroll
    for (int t = 0; t < 4; ++t) {
      int g = (wave * 4 + t) * 64 + lane;
      int krow = g >> 4, kq = ((g & 15) ^ (krow & 15)) * 8;
      async_cp16(&Kh[((size_t)kvh * S_LEN + kt * 64 + krow) * HD + kq], &Ks[(size_t)g * 8]);
      int vrow = g >> 3, vc = ((g & 7) ^ (vrow & 7)) * 8;
      async_cp16(&Vt[((size_t)(kvh * HD) + vrow) * S_LEN + kt * 64 + vc], &Vs[(size_t)g * 8]);
    }
    __syncthreads();
    f32x4 st[4] = {};
#pragma unroll
    for (int s4 = 0; s4 < 4; ++s4) {
      int row = s4 * 16 + l16;
#pragma unroll
      for (int kc = 0; kc < 4; ++kc) {
        bf16x8 a = ld_frag(&Ks[row * 128 + (((kc * 4 + quad) ^ (row & 15)) << 3)]);
        st[s4] = __builtin_amdgcn_mfma_f32_16x16x32_bf16(a, qf[kc], st[s4], 0, 0, 0);
      }
    }
    if (kt == 0) {   // per-q-row max of tile 0; never updated (scores bounded)
      float mt = st[0][0];
#pragma unroll
      for (int s4 = 0; s4 < 4; ++s4)
#pragma unroll
        for (int r = 0; r < 4; ++r) mt = fmaxf(mt, st[s4][r]);
      mt = fmaxf(mt, __shfl_xor(mt, 16));
      mt = fmaxf(mt, __shfl_xor(mt, 32));
      m = mt;
    }
    float sum = 0.f;
    unsigned pk[4][2];
#pragma unroll
    for (int s4 = 0; s4 < 4; ++s4) {
      unsigned u0 = __builtin_bit_cast(unsigned, exp2f(st[s4][0] - m)) & 0xffff0000u;
      unsigned u1 = __builtin_bit_cast(unsigned, exp2f(st[s4][1] - m)) & 0xffff0000u;
      unsigned u2 = __builtin_bit_cast(unsigned, exp2f(st[s4][2] - m)) & 0xffff0000u;
      unsigned u3 = __builtin_bit_cast(unsigned, exp2f(st[s4][3] - m)) & 0xffff0000u;
      sum += __builtin_bit_cast(float, u0) + __builtin_bit_cast(float, u1) +
             __builtin_bit_cast(float, u2) + __builtin_bit_cast(float, u3);
      pk[s4][0] = (u0 >> 16) | u1;
      pk[s4][1] = (u2 >> 16) | u3;
    }
    sum += __shfl_xor(sum, 16);
    sum += __shfl_xor(sum, 32);
    lsum += sum;
    // channel shuffles (src pushes uniform tile c; dest selects c = 2ks+(quad>>1))
    const int src0 = ((quad & 1) * 2) * 16 + l16;
    const int src1 = src0 + 16;
    unsigned sh[4][4];
#pragma unroll
    for (int c = 0; c < 4; ++c) {
      sh[c][0] = (unsigned)__shfl((int)pk[c][0], src0);
      sh[c][1] = (unsigned)__shfl((int)pk[c][1], src0);
      sh[c][2] = (unsigned)__shfl((int)pk[c][0], src1);
      sh[c][3] = (unsigned)__shfl((int)pk[c][1], src1);
    }
    const bool hi = (quad >> 1) != 0;
    bf16x8 pb[2];
#pragma unroll
    for (int ks = 0; ks < 2; ++ks) {
      union { unsigned u[4]; bf16x8 bv; } cv;
#pragma unroll
      for (int w = 0; w < 4; ++w)
        cv.u[w] = hi ? sh[2 * ks + 1][w] : sh[2 * ks][w];
      pb[ks] = cv.bv;
    }
#pragma unroll
    for (int dt = 0; dt < 8; ++dt) {
      int row = dt * 16 + l16;
#pragma unroll
      for (int ks = 0; ks < 2; ++ks) {
        bf16x8 a = ld_frag(&Vs[row * 64 + (((ks * 4 + quad) ^ (row & 7)) << 3)]);
        accO[dt] = __builtin_amdgcn_mfma_f32_16x16x32_bf16(a, pb[ks], accO[dt], 0, 0, 0);
      }
    }
    __syncthreads();
  }
  float rl = 1.f / lsum;
  const size_t orow = ((size_t)(qt * 64 + wave * 16 + l16)) * NQD + h * HD;
#pragma unroll
  for (int dt = 0; dt < 8; ++dt) {
    unsigned w0 = (unsigned)f2bf(accO[dt][0] * rl) | ((unsigned)f2bf(accO[dt][1] * rl) << 16);
    unsigned w1 = (unsigned)f2bf(accO[dt][2] * rl) | ((unsigned)f2bf(accO[dt][3] * rl) << 16);
    *(unsigned*)&O[orow + dt * 16 + quad * 4] = w0;
    *(unsigned*)&O[orow + dt * 16 + quad * 4 + 2] = w1;
  }
}

extern "C" void kernel_launch(void* const* d_in, const int* in_sizes, int n_in,
                              void* d_out, int out_size, void* d_ws, size_t ws_size,
                              hipStream_t stream) {
  const float* hidden = (const float*)d_in[0];
  const float* cosp = (const float*)d_in[1];
  const float* sinp = (const float*)d_in[2];
  const float* Wq = (const float*)d_in[3];
  const float* bq = (const float*)d_in[4];
  const float* Wk = (const float*)d_in[5];
  const float* bk = (const float*)d_in[6];
  const float* Wv = (const float*)d_in[7];
  const float* bv = (const float*)d_in[8];
  const float* Wo = (const float*)d_in[9];
  float* out = (float*)d_out;

  const size_t HID_N = (size_t)S_LEN * HDIM;
  const size_t WQ_N = (size_t)HDIM * NQD;
  const size_t KV_N = (size_t)S_LEN * NKVD;

  char* p = (char*)d_ws;
  size_t off = 0;
  auto take = [&](size_t bytes) {
    void* r = p + off; off += (bytes + 255) & ~(size_t)255; return r;
  };
  unsigned short* hid_bf = (unsigned short*)take(HID_N * 2);
  unsigned short* wqkvT = (unsigned short*)take((size_t)NQKV * HDIM * 2);
  unsigned short* woT = (unsigned short*)take(WQ_N * 2);
  float* bcat = (float*)take(NQKV * 4);
  float* cmT = (float*)take((size_t)HD * S_LEN * 4);
  float* smT = (float*)take((size_t)HD * S_LEN * 4);
  unsigned short* q_rot = (unsigned short*)take(HID_N * 2);
  unsigned short* k_rot = (unsigned short*)take(KV_N * 2);
  unsigned short* v_t = (unsigned short*)take(KV_N * 2);
  unsigned short* attn_bf = (unsigned short*)take(HID_N * 2);
  if (off > ws_size) return;   // loud failure: output stays poisoned

  cvt_kernel<<<(int)((HID_N / 4 + 255) / 256), 256, 0, stream>>>(hidden, hid_bf, (int)(HID_N / 4));
  dim3 tb(32, 8);
  tcvt<<<dim3(NQD / 32, HDIM / 32), tb, 0, stream>>>(Wq, wqkvT, HDIM, NQD, NQD);
  tcvt<<<dim3(NKVD / 32, HDIM / 32), tb, 0, stream>>>(Wk, wqkvT + (size_t)NQD * HDIM, HDIM, NKVD, NKVD);
  tcvt<<<dim3(NKVD / 32, HDIM / 32), tb, 0, stream>>>(Wv, wqkvT + (size_t)(NQD + NKVD) * HDIM, HDIM, NKVD, NKVD);
  tcvt<<<dim3(NQD / 32, NQD / 32), tb, 0, stream>>>(Wo, woT, NQD, NQD, NQD);
  biascat<<<(NQKV + 255) / 256, 256, 0, stream>>>(bq, bk, bv, bcat);
  mrope_build<<<dim3(S_LEN / 256, HD), 256, 0, stream>>>(cosp, sinp, cmT, smT);

  // fused QKV projection + rope + head-major/transposed stores
  gemm_k64<1><<<dim3(NQKV / 128, S_LEN / 128), 256, 0, stream>>>(
      hid_bf, wqkvT, bcat, cmT, smT, nullptr, q_rot, k_rot, v_t, S_LEN, NQKV, HDIM);
  // attention
  attn2<<<NH * (S_LEN / 64), 256, 0, stream>>>(q_rot, k_rot, v_t, attn_bf);
  // output projection
  gemm_k64<0><<<dim3(NQD / 128, S_LEN / 128), 256, 0, stream>>>(
      attn_bf, woT, nullptr, nullptr, nullptr, out, nullptr, nullptr, nullptr,
      S_LEN, NQD, NQD);
}